// Round 1
// baseline (514.925 us; speedup 1.0000x reference)
//
#include <hip/hip_runtime.h>

// out[b, bin, d] = ce[chr[b]-1, d], shapes: tensor (512,2001) [unused data],
// chr (512,) int32, ce (24,128) f32, out (512,2001,128) f32.
// Pure write-BW-bound broadcast: hold the 512B row in registers, stream stores.

constexpr int NBINS = 2001;   // BIN_SIZE + 1
constexpr int DIM   = 128;
constexpr int CHUNKS = 4;     // bin-range chunks per sample

__global__ __launch_bounds__(256) void chrom_embed_bcast(
    const int* __restrict__ chr,
    const float* __restrict__ ce,
    float* __restrict__ out,
    int bins_per_chunk)
{
    const int b = blockIdx.y;                 // sample index 0..BS-1
    const int row = chr[b] - 1;               // 0..23

    const int lane_f4 = threadIdx.x & 31;     // which float4 within the 128-f row
    const int sub     = threadIdx.x >> 5;     // 0..7: bin-row within the 8-row group

    // Load this thread's 16B slice of the embedding row once (L1/L2 hit).
    const float4 val = ((const float4*)(ce + (size_t)row * DIM))[lane_f4];

    int bin_start = blockIdx.x * bins_per_chunk;
    int bin_end   = bin_start + bins_per_chunk;
    if (bin_end > NBINS) bin_end = NBINS;

    float4* out_b = (float4*)(out + (size_t)b * NBINS * DIM);

    // Each iteration: 256 threads * 16B = 4KB contiguous store (8 bin-rows).
    for (int bin = bin_start + sub; bin < bin_end; bin += 8) {
        out_b[(size_t)bin * (DIM / 4) + lane_f4] = val;
    }
}

extern "C" void kernel_launch(void* const* d_in, const int* in_sizes, int n_in,
                              void* d_out, int out_size, void* d_ws, size_t ws_size,
                              hipStream_t stream)
{
    // setup_inputs order: tensor (unused), chr, ce
    const int*   chr = (const int*)d_in[1];
    const float* ce  = (const float*)d_in[2];
    float*       out = (float*)d_out;

    const int bs = in_sizes[1];                       // 512
    const int bins_per_chunk = (NBINS + CHUNKS - 1) / CHUNKS;  // 501

    dim3 grid(CHUNKS, bs);
    chrom_embed_bcast<<<grid, 256, 0, stream>>>(chr, ce, out, bins_per_chunk);
}

// Round 3
// 511.954 us; speedup vs baseline: 1.0058x; 1.0058x over previous
//
#include <hip/hip_runtime.h>

// out[b, bin, d] = ce[chr[b]-1, d]; tensor (512,2001) unused, chr (512,) i32,
// ce (24,128) f32, out (512,2001,128) f32 = 524.5 MB. Pure write-BW-bound.
// v3: same as v2 but with a native vector type for __builtin_nontemporal_store
// (HIP's float4 class is rejected by the builtin; ext_vector_type works and
// still emits global_store_dwordx4 nt).

constexpr int NBINS  = 2001;  // BIN_SIZE + 1
constexpr int DIM    = 128;
constexpr int CHUNKS = 4;     // bin-range chunks per sample -> 2048 blocks

typedef float v4f __attribute__((ext_vector_type(4)));

__global__ __launch_bounds__(256) void chrom_embed_bcast(
    const int* __restrict__ chr,
    const float* __restrict__ ce,
    float* __restrict__ out,
    int bins_per_chunk)
{
    const int b   = blockIdx.y;        // sample 0..511
    const int row = chr[b] - 1;        // 0..23

    const int lane_f4 = threadIdx.x & 31;   // float4 slot within the 128-f row
    const int sub     = threadIdx.x >> 5;   // 0..7: bin-row within 8-row group

    const v4f val = ((const v4f*)(ce + (size_t)row * DIM))[lane_f4];

    int bin_start = blockIdx.x * bins_per_chunk;
    int bin_end   = bin_start + bins_per_chunk;
    if (bin_end > NBINS) bin_end = NBINS;

    v4f* out_b = (v4f*)(out + (size_t)b * NBINS * DIM);

    // Main loop: 4 independent 16B nt-stores per thread per iteration.
    // Block covers 8 bins per sub-step; unroll 4 -> 32 bins/iter, 16KB/block/iter.
    int bin = bin_start + sub;
    for (; bin + 24 < bin_end; bin += 32) {
        __builtin_nontemporal_store(val, &out_b[(size_t)(bin     ) * (DIM / 4) + lane_f4]);
        __builtin_nontemporal_store(val, &out_b[(size_t)(bin +  8) * (DIM / 4) + lane_f4]);
        __builtin_nontemporal_store(val, &out_b[(size_t)(bin + 16) * (DIM / 4) + lane_f4]);
        __builtin_nontemporal_store(val, &out_b[(size_t)(bin + 24) * (DIM / 4) + lane_f4]);
    }
    for (; bin < bin_end; bin += 8) {
        __builtin_nontemporal_store(val, &out_b[(size_t)bin * (DIM / 4) + lane_f4]);
    }
}

extern "C" void kernel_launch(void* const* d_in, const int* in_sizes, int n_in,
                              void* d_out, int out_size, void* d_ws, size_t ws_size,
                              hipStream_t stream)
{
    // setup_inputs order: tensor (unused), chr, ce
    const int*   chr = (const int*)d_in[1];
    const float* ce  = (const float*)d_in[2];
    float*       out = (float*)d_out;

    const int bs = in_sizes[1];                                // 512
    const int bins_per_chunk = (NBINS + CHUNKS - 1) / CHUNKS;  // 501

    dim3 grid(CHUNKS, bs);
    chrom_embed_bcast<<<grid, 256, 0, stream>>>(chr, ce, out, bins_per_chunk);
}